// Round 12
// baseline (432.908 us; speedup 1.0000x reference)
//
#include <hip/hip_runtime.h>
#include <hip/hip_cooperative_groups.h>
#include <stdint.h>

namespace cg = cooperative_groups;

typedef unsigned short u16;
typedef __bf16 bf16x8 __attribute__((ext_vector_type(8)));
typedef float f32x4 __attribute__((ext_vector_type(4)));

__device__ __forceinline__ float b2f(u16 u) {
    unsigned x = ((unsigned)u) << 16;
    return __builtin_bit_cast(float, x);
}
__device__ __forceinline__ u16 f2b(float f) {
    unsigned x = __builtin_bit_cast(unsigned, f);
    x = x + 0x7fffu + ((x >> 16) & 1u);
    return (u16)(x >> 16);
}
__device__ __forceinline__ float leaky(float v) { return v > 0.f ? v : 0.2f * v; }
__device__ __forceinline__ float elu(float v) { return v > 0.f ? v : expm1f(v); }

__device__ __forceinline__ void gload16(const u16* g, u16* l) {
    __builtin_amdgcn_global_load_lds((const __attribute__((address_space(1))) void*)(const void*)g,
                                     (__attribute__((address_space(3))) void*)(void*)l, 16, 0, 0);
}

// ---------------- k_pre: x-cast + deg-zero + detect + both weight transposes ----------------
// blocks [0,2048): cast4 grid-stride + deg zero; block 0 also runs int64-detect.
// blocks [2048,2944): weight transpose tiles (768 for W1, 128 for W2).
__global__ void k_pre(const float* __restrict__ x, u16* __restrict__ xb,
                      const float* __restrict__ W1, u16* __restrict__ w1t,
                      const float* __restrict__ W2, u16* __restrict__ w2t,
                      const int* __restrict__ ei, int* __restrict__ flag,
                      int* __restrict__ deg, size_t n4, int E0, int N) {
    int bid = blockIdx.x, t = threadIdx.x;
    if (bid < 2048) {
        size_t i = (size_t)bid * 256 + t;
        const size_t stride = (size_t)2048 * 256;
        for (size_t k = i; k < n4; k += stride) {
            float4 v = ((const float4*)x)[k];
            ushort4 o;
            o.x = f2b(v.x); o.y = f2b(v.y); o.z = f2b(v.z); o.w = f2b(v.w);
            ((ushort4*)xb)[k] = o;
        }
        for (size_t k = i; k < (size_t)N; k += stride) deg[k] = 0;
        if (bid == 0) {
            if (t == 0) *flag = 0;
            __syncthreads();
            int lim = E0 < 4096 ? E0 : 4096;
            int any = 0;
            for (int k = t; k < lim; k += 256) any |= (ei[2 * k + 1] != 0);
            if (any) atomicOr(flag, 1);
        }
    } else {
        __shared__ float tile[32][33];
        int b = bid - 2048;
        const float* in; u16* outp; int R, C, cx, ry;
        if (b < 768) { in = W1; outp = w1t; R = 768; C = 1024; cx = b & 31; ry = b >> 5; }
        else { int b2 = b - 768; in = W2; outp = w2t; R = 1024; C = 128; cx = b2 & 3; ry = b2 >> 2; }
        int tx = t & 31, ty = t >> 5;
        int c0 = cx * 32, r0 = ry * 32;
        #pragma unroll
        for (int i = 0; i < 32; i += 8)
            tile[ty + i][tx] = in[(size_t)(r0 + ty + i) * C + c0 + tx];
        __syncthreads();
        #pragma unroll
        for (int i = 0; i < 32; i += 8)
            outp[(size_t)(c0 + ty + i) * R + r0 + tx] = f2b(tile[tx][ty + i]);
    }
}

// ---------------- k_csr (cooperative): deg -> scan -> scatter in one kernel ----------------
__global__ __launch_bounds__(256) void k_csr(const int* __restrict__ ei, const int* __restrict__ flag,
                                             int* __restrict__ deg, int* __restrict__ off,
                                             int* __restrict__ cursor, int* __restrict__ csr,
                                             int* __restrict__ bsum, int* __restrict__ bbase,
                                             int E0, int E, int N) {
    cg::grid_group grid = cg::this_grid();
    __shared__ int s[256];
    int t = threadIdx.x, b = blockIdx.x;
    int gid = b * 256 + t, gsz = gridDim.x * 256;
    bool i64 = (*flag == 0);
    // phase 1: degree histogram
    for (int e = gid; e < E; e += gsz) {
        int d;
        if (e < E0) d = i64 ? ei[2 * (E0 + e)] : ei[E0 + e];
        else d = e - E0;
        atomicAdd(&deg[d], 1);
    }
    grid.sync();
    // phase 2: block-local inclusive scan over this block's 256 nodes
    int idx = gid;
    int v = (idx < N) ? deg[idx] : 0;
    s[t] = v;
    __syncthreads();
    #pragma unroll
    for (int d = 1; d < 256; d <<= 1) {
        int x = (t >= d) ? s[t - d] : 0;
        __syncthreads();
        s[t] += x;
        __syncthreads();
    }
    int incl = s[t];
    if (t == 255) bsum[b] = incl;
    grid.sync();
    // phase 3: block 0 exclusive-scans the block sums
    if (b == 0) {
        int nb = gridDim.x;
        int bv = (t < nb) ? bsum[t] : 0;
        s[t] = bv;
        __syncthreads();
        #pragma unroll
        for (int d = 1; d < 256; d <<= 1) {
            int x = (t >= d) ? s[t - d] : 0;
            __syncthreads();
            s[t] += x;
            __syncthreads();
        }
        if (t < nb) bbase[t] = s[t] - bv;
        if (t == 0) off[N] = E;
    }
    grid.sync();
    // phase 4: write offsets + cursor
    int excl = bbase[b] + incl - v;
    if (idx < N) { off[idx] = excl; cursor[idx] = excl; }
    grid.sync();
    // phase 5: scatter
    for (int e = gid; e < E; e += gsz) {
        int sv, d;
        if (e < E0) {
            if (i64) { sv = ei[2 * e]; d = ei[2 * (E0 + e)]; }
            else     { sv = ei[e];     d = ei[E0 + e]; }
        } else { sv = d = e - E0; }
        int pos = atomicAdd(&cursor[d], 1);
        csr[pos] = sv;
    }
}

// ---------------- GEMM1: C[M,NN] = A[M,K] * Bt[NN,K]^T (bf16), gload_lds + swizzle ----------
#define GBM 128
#define GBN 128
#define GBK 64
#define LDT 72
#define SPLITK 4

__global__ __launch_bounds__(256) void k_gemm(const u16* __restrict__ A, const u16* __restrict__ Bt,
                                              u16* __restrict__ C, int M, int NN, int K, int nCB) {
    __shared__ __align__(16) u16 As[GBM][GBK];
    __shared__ __align__(16) u16 Bs[GBN][GBK];
    int nwg = gridDim.x, orig = blockIdx.x;
    int q = nwg >> 3, r8 = nwg & 7, xcd = orig & 7, sub = orig >> 3;
    int wgid = (xcd < r8 ? xcd * (q + 1) : r8 * (q + 1) + (xcd - r8) * q) + sub;
    int rb = wgid / nCB, cb = wgid % nCB;
    int brow = rb * GBM, bcol = cb * GBN;

    int t = threadIdx.x, lane = t & 63, wid = t >> 6;
    int wm = (wid >> 1) * 64, wn = (wid & 1) * 64;
    int fr = lane & 15, fq = lane >> 4;
    f32x4 acc[4][4] = {};
    int srow = lane >> 3;
    int scol = (((lane & 7) ^ srow)) * 8;
    int dcol = (lane & 7) * 8;
    int nK = K / GBK;
    for (int kt = 0; kt < nK; ++kt) {
        int k0 = kt * GBK;
        #pragma unroll
        for (int cc = 0; cc < 8; ++cc) {
            int c = wid * 8 + cc;
            int r = (c & 15) * 8 + srow;
            if (c < 16) gload16(A + (size_t)(brow + r) * K + k0 + scol, &As[r][dcol]);
            else        gload16(Bt + (size_t)(bcol + r) * K + k0 + scol, &Bs[r][dcol]);
        }
        __syncthreads();
        #pragma unroll
        for (int kk = 0; kk < 2; ++kk) {
            int ko = kk * 32 + fq * 8;
            int kos = ko ^ ((fr & 7) << 3);
            bf16x8 af[4], bg[4];
            #pragma unroll
            for (int i = 0; i < 4; ++i) {
                af[i] = *reinterpret_cast<const bf16x8*>(&As[wm + i * 16 + fr][kos]);
                bg[i] = *reinterpret_cast<const bf16x8*>(&Bs[wn + i * 16 + fr][kos]);
            }
            #pragma unroll
            for (int mi = 0; mi < 4; ++mi)
                #pragma unroll
                for (int ni = 0; ni < 4; ++ni)
                    acc[mi][ni] = __builtin_amdgcn_mfma_f32_16x16x32_bf16(af[mi], bg[ni], acc[mi][ni], 0, 0, 0);
        }
        __syncthreads();
    }
    #pragma unroll
    for (int mi = 0; mi < 4; ++mi) {
        #pragma unroll
        for (int j = 0; j < 4; ++j) {
            int row = brow + wm + mi * 16 + fq * 4 + j;
            if (row < M) {
                #pragma unroll
                for (int ni = 0; ni < 4; ++ni) {
                    int col = bcol + wn + ni * 16 + fr;
                    C[(size_t)row * NN + col] = f2b(acc[mi][ni][j]);
                }
            }
        }
    }
}

// ---------------- GEMM2 split-K: partial[ks][M][128] f32, BN1+ELU fused on A-staging ----------
__global__ __launch_bounds__(256) void k_gemm2(const u16* __restrict__ A, const u16* __restrict__ Bt,
                                               float* __restrict__ Cp, int M, int K,
                                               const float* __restrict__ scA, const float* __restrict__ shA) {
    __shared__ __align__(16) u16 As[GBM][LDT];
    __shared__ __align__(16) u16 Bs[GBN][LDT];
    int brow = blockIdx.x * GBM;
    int ks = blockIdx.y;
    int kBase = ks * (K / SPLITK);
    int t = threadIdx.x;
    int lane = t & 63, wid = t >> 6;
    int wm = (wid >> 1) * 64, wn = (wid & 1) * 64;
    int fr = lane & 15, fq = lane >> 4;
    f32x4 acc[4][4] = {};
    int tr = t >> 3, tc = (t & 7) * 8;
    const int nK = 1024 / SPLITK / GBK;  // 4
    for (int kt = 0; kt < nK; ++kt) {
        int k0 = kBase + kt * GBK;
        #pragma unroll
        for (int rr = 0; rr < 4; ++rr) {
            int r = tr + rr * 32;
            int grow = brow + r;
            uint4 bv = *reinterpret_cast<const uint4*>(Bt + (size_t)r * K + k0 + tc);
            *reinterpret_cast<uint4*>(&Bs[r][tc]) = bv;
            uint4 av = make_uint4(0, 0, 0, 0);
            if (grow < M) {
                uint4 u = *reinterpret_cast<const uint4*>(A + (size_t)grow * K + k0 + tc);
                float4 s0 = *(const float4*)(scA + k0 + tc);
                float4 s1 = *(const float4*)(scA + k0 + tc + 4);
                float4 h0 = *(const float4*)(shA + k0 + tc);
                float4 h1 = *(const float4*)(shA + k0 + tc + 4);
                u16 w0 = f2b(elu(b2f((u16)(u.x & 0xffff)) * s0.x + h0.x));
                u16 w1 = f2b(elu(b2f((u16)(u.x >> 16))    * s0.y + h0.y));
                u16 w2 = f2b(elu(b2f((u16)(u.y & 0xffff)) * s0.z + h0.z));
                u16 w3 = f2b(elu(b2f((u16)(u.y >> 16))    * s0.w + h0.w));
                u16 w4 = f2b(elu(b2f((u16)(u.z & 0xffff)) * s1.x + h1.x));
                u16 w5 = f2b(elu(b2f((u16)(u.z >> 16))    * s1.y + h1.y));
                u16 w6 = f2b(elu(b2f((u16)(u.w & 0xffff)) * s1.z + h1.z));
                u16 w7 = f2b(elu(b2f((u16)(u.w >> 16))    * s1.w + h1.w));
                av.x = (unsigned)w0 | ((unsigned)w1 << 16);
                av.y = (unsigned)w2 | ((unsigned)w3 << 16);
                av.z = (unsigned)w4 | ((unsigned)w5 << 16);
                av.w = (unsigned)w6 | ((unsigned)w7 << 16);
            }
            *reinterpret_cast<uint4*>(&As[r][tc]) = av;
        }
        __syncthreads();
        #pragma unroll
        for (int kk = 0; kk < 2; ++kk) {
            int ko = kk * 32 + fq * 8;
            bf16x8 af[4], bg[4];
            #pragma unroll
            for (int i = 0; i < 4; ++i) {
                af[i] = *reinterpret_cast<const bf16x8*>(&As[wm + i * 16 + fr][ko]);
                bg[i] = *reinterpret_cast<const bf16x8*>(&Bs[wn + i * 16 + fr][ko]);
            }
            #pragma unroll
            for (int mi = 0; mi < 4; ++mi)
                #pragma unroll
                for (int ni = 0; ni < 4; ++ni)
                    acc[mi][ni] = __builtin_amdgcn_mfma_f32_16x16x32_bf16(af[mi], bg[ni], acc[mi][ni], 0, 0, 0);
        }
        __syncthreads();
    }
    float* base = Cp + (size_t)ks * M * 128;
    #pragma unroll
    for (int mi = 0; mi < 4; ++mi) {
        #pragma unroll
        for (int j = 0; j < 4; ++j) {
            int row = brow + wm + mi * 16 + fq * 4 + j;
            if (row < M) {
                #pragma unroll
                for (int ni = 0; ni < 4; ++ni) {
                    int col = wn + ni * 16 + fr;
                    base[(size_t)row * 128 + col] = acc[mi][ni][j];
                }
            }
        }
    }
}

// ---------------- reduce split-K partials -> bf16 h2 + fused att1 dots ----------------
__global__ __launch_bounds__(256) void k_red2(const float* __restrict__ Cp,
                                              const float* __restrict__ attS, const float* __restrict__ attD,
                                              u16* __restrict__ h2b, float* __restrict__ asrc,
                                              float* __restrict__ adst, int M) {
    int t = threadIdx.x, lane = t & 63, wid = t >> 6;
    int row = blockIdx.x * 4 + wid;
    if (row >= M) return;
    int c = lane * 2;
    float s0 = 0.f, s1 = 0.f;
    #pragma unroll
    for (int s = 0; s < SPLITK; ++s) {
        float2 v = *(const float2*)(Cp + ((size_t)s * M + row) * 128 + c);
        s0 += v.x; s1 += v.y;
    }
    ushort2 o; o.x = f2b(s0); o.y = f2b(s1);
    *(ushort2*)(h2b + (size_t)row * 128 + c) = o;
    float ps = s0 * attS[c] + s1 * attS[c + 1];
    float pd = s0 * attD[c] + s1 * attD[c + 1];
    #pragma unroll
    for (int m = 1; m < 64; m <<= 1) { ps += __shfl_xor(ps, m); pd += __shfl_xor(pd, m); }
    if (lane == 0) { asrc[row] = ps; adst[row] = pd; }
}

// ---------------- attention dots (layer 1) ----------------
__global__ void k_att8(const u16* __restrict__ h, const float* __restrict__ attS,
                       const float* __restrict__ attD, float* __restrict__ asrc,
                       float* __restrict__ adst, int N) {
    int t = threadIdx.x;
    int half = t >> 7, i = t & 127;
    int row = blockIdx.x * 2 + half;
    if (row >= N) return;
    int head = i >> 4, g = i & 15;
    const u16* hp = h + (size_t)row * 1024 + head * 128 + g * 8;
    const float* sp = attS + head * 128 + g * 8;
    const float* dp = attD + head * 128 + g * 8;
    ushort4 u0 = *(const ushort4*)hp;
    ushort4 u1 = *(const ushort4*)(hp + 4);
    float hv[8] = {b2f(u0.x), b2f(u0.y), b2f(u0.z), b2f(u0.w),
                   b2f(u1.x), b2f(u1.y), b2f(u1.z), b2f(u1.w)};
    float ps = 0.f, pd = 0.f;
    #pragma unroll
    for (int j = 0; j < 8; ++j) { ps += hv[j] * sp[j]; pd += hv[j] * dp[j]; }
    #pragma unroll
    for (int m = 1; m < 16; m <<= 1) { ps += __shfl_xor(ps, m); pd += __shfl_xor(pd, m); }
    if (g == 0) { asrc[row * 8 + head] = ps; adst[row * 8 + head] = pd; }
}

// ---------------- layer-1 aggregation with wave0-computed softmax in LDS ----------------
__global__ __launch_bounds__(256) void k_agg1(const int* __restrict__ off, const int* __restrict__ csr,
                                              const float* __restrict__ asrc, const float* __restrict__ adst,
                                              const u16* __restrict__ h1, u16* __restrict__ outg, int N) {
    __shared__ float pch[64][8];
    __shared__ float invs[8];
    int node = blockIdx.x;
    if (node >= N) return;
    int t = threadIdx.x, lane = t & 63, wid = t >> 6;
    int hh = t >> 5;
    int c0 = t * 4;
    int lo = off[node], hi = off[node + 1];
    float ad_l = 0.f, mmax = -1e30f, ssum = 0.f;
    int h = lane & 7, es = lane >> 3;
    if (wid == 0) {
        ad_l = adst[(size_t)node * 8 + h];
        for (int i = lo + es; i < hi; i += 8)
            mmax = fmaxf(mmax, leaky(asrc[(size_t)csr[i] * 8 + h] + ad_l));
        #pragma unroll
        for (int mask = 8; mask < 64; mask <<= 1) mmax = fmaxf(mmax, __shfl_xor(mmax, mask));
    }
    float a0 = 0.f, a1 = 0.f, a2 = 0.f, a3 = 0.f;
    for (int base = lo; base < hi; base += 64) {
        int cend = base + 64 < hi ? base + 64 : hi;
        if (wid == 0) {
            for (int i = base + es; i < cend; i += 8) {
                float p = __expf(leaky(asrc[(size_t)csr[i] * 8 + h] + ad_l) - mmax);
                pch[i - base][h] = p;
                ssum += p;
            }
        }
        __syncthreads();
        for (int i = base; i < cend; ++i) {
            float p = pch[i - base][hh];
            ushort4 u = *(const ushort4*)(h1 + (size_t)csr[i] * 1024 + c0);
            a0 += p * b2f(u.x); a1 += p * b2f(u.y);
            a2 += p * b2f(u.z); a3 += p * b2f(u.w);
        }
        __syncthreads();
    }
    if (wid == 0) {
        #pragma unroll
        for (int mask = 8; mask < 64; mask <<= 1) ssum += __shfl_xor(ssum, mask);
        if (lane < 8) invs[lane] = 1.f / (ssum + 1e-16f);
    }
    __syncthreads();
    float inv = invs[hh];
    ushort4 o;
    o.x = f2b(a0 * inv); o.y = f2b(a1 * inv); o.z = f2b(a2 * inv); o.w = f2b(a3 * inv);
    *(ushort4*)(outg + (size_t)node * 1024 + c0) = o;
}

// ---------------- layer-2 aggregation with fused softmax (128 threads = 1 node) ----------------
__global__ __launch_bounds__(128) void k_agg2(const int* __restrict__ off, const int* __restrict__ csr,
                                              const float* __restrict__ asrc, const float* __restrict__ adst,
                                              const u16* __restrict__ h2, u16* __restrict__ outg, int N) {
    __shared__ float pch[64];
    __shared__ float invsh;
    int node = blockIdx.x;
    if (node >= N) return;
    int t = threadIdx.x, lane = t & 63, wid = t >> 6;
    int lo = off[node], hi = off[node + 1];
    float ad = adst[node];
    float mmax = -1e30f, ssum = 0.f;
    if (wid == 0) {
        for (int i = lo + lane; i < hi; i += 64)
            mmax = fmaxf(mmax, leaky(asrc[csr[i]] + ad));
        #pragma unroll
        for (int mask = 1; mask < 64; mask <<= 1) mmax = fmaxf(mmax, __shfl_xor(mmax, mask));
    }
    float acc = 0.f;
    for (int base = lo; base < hi; base += 64) {
        int cend = base + 64 < hi ? base + 64 : hi;
        if (wid == 0 && base + lane < cend) {
            float p = __expf(leaky(asrc[csr[base + lane]] + ad) - mmax);
            pch[lane] = p;
            ssum += p;
        }
        __syncthreads();
        for (int i = base; i < cend; ++i)
            acc += pch[i - base] * b2f(h2[(size_t)csr[i] * 128 + t]);
        __syncthreads();
    }
    if (wid == 0) {
        #pragma unroll
        for (int mask = 1; mask < 64; mask <<= 1) ssum += __shfl_xor(ssum, mask);
        if (lane == 0) invsh = 1.f / (ssum + 1e-16f);
    }
    __syncthreads();
    outg[(size_t)node * 128 + t] = f2b(acc * invsh);
}

// ---------------- k_bn1 (cooperative): BN stats for CH=1024 (part + final) ----------------
__global__ __launch_bounds__(256) void k_bn1(const u16* __restrict__ g, const float* __restrict__ gamma,
                                             const float* __restrict__ beta, float* __restrict__ ps,
                                             float* __restrict__ ps2, float* __restrict__ scale,
                                             float* __restrict__ shift, int Nrows) {
    cg::grid_group grid = cg::this_grid();
    int t = threadIdx.x;
    int c4 = t * 4;
    int chunk = blockIdx.x;                     // 256 blocks
    int rpc = (Nrows + gridDim.x - 1) / gridDim.x;
    int r0 = chunk * rpc;
    int r1 = r0 + rpc; if (r1 > Nrows) r1 = Nrows;
    float s[4] = {0.f, 0.f, 0.f, 0.f}, q[4] = {0.f, 0.f, 0.f, 0.f};
    for (int r = r0; r < r1; ++r) {
        ushort4 u = *(const ushort4*)(g + (size_t)r * 1024 + c4);
        float v0 = b2f(u.x), v1 = b2f(u.y), v2 = b2f(u.z), v3 = b2f(u.w);
        s[0] += v0; q[0] += v0 * v0;
        s[1] += v1; q[1] += v1 * v1;
        s[2] += v2; q[2] += v2 * v2;
        s[3] += v3; q[3] += v3 * v3;
    }
    *(float4*)(ps + (size_t)chunk * 1024 + c4)  = make_float4(s[0], s[1], s[2], s[3]);
    *(float4*)(ps2 + (size_t)chunk * 1024 + c4) = make_float4(q[0], q[1], q[2], q[3]);
    grid.sync();
    int lane = t & 63, wid = t >> 6;
    int col = blockIdx.x * 4 + wid;             // 256*4 = 1024 cols
    float fs = 0.f, fq = 0.f;
    int P = gridDim.x;
    for (int p = lane; p < P; p += 64) {
        fs += ps[(size_t)p * 1024 + col];
        fq += ps2[(size_t)p * 1024 + col];
    }
    #pragma unroll
    for (int m = 1; m < 64; m <<= 1) { fs += __shfl_xor(fs, m); fq += __shfl_xor(fq, m); }
    if (lane == 0) {
        double mu = (double)fs / Nrows;
        double var = (double)fq / Nrows - mu * mu;
        if (var < 0) var = 0;
        float sc = gamma[col] * rsqrtf((float)var + 1e-5f);
        scale[col] = sc;
        shift[col] = beta[col] - (float)mu * sc;
    }
}

// ---------------- k_bn2 (cooperative): BN stats for CH=128 (part + final) ----------------
__global__ __launch_bounds__(256) void k_bn2(const u16* __restrict__ g, const float* __restrict__ gamma,
                                             const float* __restrict__ beta, float* __restrict__ ps,
                                             float* __restrict__ ps2, float* __restrict__ scale,
                                             float* __restrict__ shift, int Nrows) {
    cg::grid_group grid = cg::this_grid();
    int t = threadIdx.x;
    int rl = t >> 5, c4 = (t & 31) * 4;
    int chunk = blockIdx.x;                     // 128 blocks
    int rpc = (Nrows + gridDim.x - 1) / gridDim.x;
    int r0 = chunk * rpc;
    int r1 = r0 + rpc; if (r1 > Nrows) r1 = Nrows;
    float s[4] = {0.f, 0.f, 0.f, 0.f}, q[4] = {0.f, 0.f, 0.f, 0.f};
    for (int r = r0 + rl; r < r1; r += 8) {
        ushort4 u = *(const ushort4*)(g + (size_t)r * 128 + c4);
        float v0 = b2f(u.x), v1 = b2f(u.y), v2 = b2f(u.z), v3 = b2f(u.w);
        s[0] += v0; q[0] += v0 * v0;
        s[1] += v1; q[1] += v1 * v1;
        s[2] += v2; q[2] += v2 * v2;
        s[3] += v3; q[3] += v3 * v3;
    }
    size_t prow = (size_t)(chunk * 8 + rl) * 128 + c4;
    *(float4*)(ps + prow)  = make_float4(s[0], s[1], s[2], s[3]);
    *(float4*)(ps2 + prow) = make_float4(q[0], q[1], q[2], q[3]);
    grid.sync();
    int lane = t & 63, wid = t >> 6;
    if (wid == 0) {
        int col = blockIdx.x;                   // 128 cols
        int P = gridDim.x * 8;                  // 1024 partial rows
        float fs = 0.f, fq = 0.f;
        for (int p = lane; p < P; p += 64) {
            fs += ps[(size_t)p * 128 + col];
            fq += ps2[(size_t)p * 128 + col];
        }
        #pragma unroll
        for (int m = 1; m < 64; m <<= 1) { fs += __shfl_xor(fs, m); fq += __shfl_xor(fq, m); }
        if (lane == 0) {
            double mu = (double)fs / Nrows;
            double var = (double)fq / Nrows - mu * mu;
            if (var < 0) var = 0;
            float sc = gamma[col] * rsqrtf((float)var + 1e-5f);
            scale[col] = sc;
            shift[col] = beta[col] - (float)mu * sc;
        }
    }
}

// ---------------- classifier (fused BN2+ELU on load, 64 rows/block) ----------------
__global__ __launch_bounds__(256) void k_cls(const u16* __restrict__ g2raw,
                                             const float* __restrict__ scale2, const float* __restrict__ shift2,
                                             const float* __restrict__ Wc1, const float* __restrict__ bc1,
                                             const float* __restrict__ Wc2, const float* __restrict__ bc2,
                                             float* __restrict__ out, int N) {
    __shared__ float wl[128 * 64];
    __shared__ float hs[4][128];
    int t = threadIdx.x, lane = t & 63, wid = t >> 6;
    for (int i = t; i < 128 * 64; i += 256) wl[i] = Wc1[i];
    float sc0 = scale2[2 * lane], sc1 = scale2[2 * lane + 1];
    float sh0 = shift2[2 * lane], sh1 = shift2[2 * lane + 1];
    float bb = bc1[lane];
    float c2a = Wc2[lane * 2], c2b = Wc2[lane * 2 + 1];
    float o2a = bc2[0], o2b = bc2[1];
    __syncthreads();
    int row0 = blockIdx.x * 64;
    for (int it = 0; it < 16; ++it) {
        int row = row0 + it * 4 + wid;
        if (row >= N) continue;
        const u16* hp = g2raw + (size_t)row * 128 + 2 * lane;
        float y0 = b2f(hp[0]) * sc0 + sh0; y0 = y0 > 0.f ? y0 : expm1f(y0);
        float y1 = b2f(hp[1]) * sc1 + sh1; y1 = y1 > 0.f ? y1 : expm1f(y1);
        hs[wid][2 * lane] = y0;
        hs[wid][2 * lane + 1] = y1;
        float tj = bb;
        #pragma unroll 8
        for (int c = 0; c < 128; ++c) tj += hs[wid][c] * wl[c * 64 + lane];
        tj = tj > 0.f ? tj : expm1f(tj);
        float v0 = tj * c2a, v1 = tj * c2b;
        #pragma unroll
        for (int m = 1; m < 64; m <<= 1) { v0 += __shfl_xor(v0, m); v1 += __shfl_xor(v1, m); }
        if (lane == 0) {
            out[(size_t)row * 2 + 0] = v0 + o2a;
            out[(size_t)row * 2 + 1] = v1 + o2b;
        }
    }
}

// ---------------- host launch ----------------
extern "C" void kernel_launch(void* const* d_in, const int* in_sizes, int n_in,
                              void* d_out, int out_size, void* d_ws, size_t ws_size,
                              hipStream_t stream) {
    const float* x     = (const float*)d_in[0];
    const int*   ei    = (const int*)d_in[1];
    const float* W1    = (const float*)d_in[2];
    const float* attS1 = (const float*)d_in[3];
    const float* attD1 = (const float*)d_in[4];
    const float* bn1g  = (const float*)d_in[6];
    const float* bn1b  = (const float*)d_in[7];
    const float* W2    = (const float*)d_in[8];
    const float* attS2 = (const float*)d_in[9];
    const float* attD2 = (const float*)d_in[10];
    const float* bn2g  = (const float*)d_in[12];
    const float* bn2b  = (const float*)d_in[13];
    const float* Wc1   = (const float*)d_in[14];
    const float* bc1   = (const float*)d_in[15];
    const float* Wc2   = (const float*)d_in[16];
    const float* bc2   = (const float*)d_in[17];
    float* out = (float*)d_out;

    const int DIN = 768, F1 = 1024, C2 = 128;
    int N = in_sizes[0] / DIN;                  // 20000
    int E0 = in_sizes[1] / 2;                   // 160000
    int E = E0 + N;
    const int nMB = (N + GBM - 1) / GBM;        // 157 row-blocks
    const int Mp = nMB * GBM;                   // 20096 padded rows

    char* w = (char*)d_ws;
    auto take = [&](size_t bytes) -> void* {
        void* p = (void*)w;
        w += (bytes + 255) & ~(size_t)255;
        return p;
    };
    u16* xb     = (u16*)take((size_t)Mp * DIN * 2);
    u16* bufA   = (u16*)take((size_t)N * F1 * 2);
    u16* h1b    = (u16*)take((size_t)N * F1 * 2);
    u16* w1t    = (u16*)take((size_t)F1 * DIN * 2);
    u16* w2t    = (u16*)take((size_t)C2 * F1 * 2);
    float* asrc1 = (float*)take((size_t)N * 8 * 4);
    float* adst1 = (float*)take((size_t)N * 8 * 4);
    int* deg    = (int*)take((size_t)N * 4);
    int* off    = (int*)take((size_t)(N + 1) * 4);
    int* cursor = (int*)take((size_t)N * 4);
    int* csr    = (int*)take((size_t)E * 4);
    int* flag   = (int*)take(256);
    int* bsum   = (int*)take(256 * 4);
    int* bbase  = (int*)take(256 * 4);
    u16* h2b    = (u16*)take((size_t)N * C2 * 2);
    float* asrc2 = (float*)take((size_t)N * 4);
    float* adst2 = (float*)take((size_t)N * 4);
    u16* g2     = (u16*)take((size_t)N * C2 * 2);
    float* scale1 = (float*)take(F1 * 4);
    float* shift1 = (float*)take(F1 * 4);
    float* scale2 = (float*)take(C2 * 4);
    float* shift2 = (float*)take(C2 * 4);
    float* psA   = (float*)take((size_t)1024 * 1024 * 4);
    float* psB   = (float*)take((size_t)1024 * 1024 * 4);
    float* part  = (float*)h1b;  // split-K partials alias h1b (dead after k_agg1)

    size_t n4 = (size_t)N * DIN / 4;

    // 1. pre: cast + deg-zero + detect + weight transposes
    k_pre<<<2048 + 896, 256, 0, stream>>>(x, xb, W1, w1t, W2, w2t, ei, flag, deg, n4, E0, N);

    // 2. CSR build (cooperative: deg -> scan -> scatter)
    {
        int NB = (N + 255) / 256;  // 79
        void* args[] = {&ei, &flag, &deg, &off, &cursor, &csr, &bsum, &bbase, &E0, &E, &N};
        hipLaunchCooperativeKernel(reinterpret_cast<void*>(k_csr), dim3(NB), dim3(256), args, 0, stream);
    }

    // 3. layer 1 GEMM + att dots
    k_gemm<<<nMB * (F1 / GBN), 256, 0, stream>>>(xb, w1t, h1b, N, F1, DIN, F1 / GBN);
    k_att8<<<(N + 1) / 2, 256, 0, stream>>>(h1b, attS1, attD1, asrc1, adst1, N);

    // 4. layer 1 aggregation + BN stats (cooperative)
    k_agg1<<<N, 256, 0, stream>>>(off, csr, asrc1, adst1, h1b, bufA, N);
    {
        void* args[] = {&bufA, &bn1g, &bn1b, &psA, &psB, &scale1, &shift1, &N};
        hipLaunchCooperativeKernel(reinterpret_cast<void*>(k_bn1), dim3(256), dim3(256), args, 0, stream);
    }

    // 5. layer 2 GEMM (split-K, BN1+ELU fused) + reduce + att dots
    k_gemm2<<<dim3(nMB, SPLITK), 256, 0, stream>>>(bufA, w2t, part, N, F1, scale1, shift1);
    k_red2<<<(N + 3) / 4, 256, 0, stream>>>(part, attS2, attD2, h2b, asrc2, adst2, N);

    // 6. layer 2 aggregation + BN stats (cooperative)
    k_agg2<<<N, 128, 0, stream>>>(off, csr, asrc2, adst2, h2b, g2, N);
    {
        void* args[] = {&g2, &bn2g, &bn2b, &psA, &psB, &scale2, &shift2, &N};
        hipLaunchCooperativeKernel(reinterpret_cast<void*>(k_bn2), dim3(128), dim3(256), args, 0, stream);
    }

    // 7. classifier head (fused BN2+ELU)
    k_cls<<<(N + 63) / 64, 256, 0, stream>>>(g2, scale2, shift2, Wc1, bc1, Wc2, bc2, out, N);
}

// Round 13
// 340.683 us; speedup vs baseline: 1.2707x; 1.2707x over previous
//
#include <hip/hip_runtime.h>
#include <stdint.h>

typedef unsigned short u16;
typedef __bf16 bf16x8 __attribute__((ext_vector_type(8)));
typedef float f32x4 __attribute__((ext_vector_type(4)));

__device__ __forceinline__ float b2f(u16 u) {
    unsigned x = ((unsigned)u) << 16;
    return __builtin_bit_cast(float, x);
}
__device__ __forceinline__ u16 f2b(float f) {
    unsigned x = __builtin_bit_cast(unsigned, f);
    x = x + 0x7fffu + ((x >> 16) & 1u);
    return (u16)(x >> 16);
}
__device__ __forceinline__ float leaky(float v) { return v > 0.f ? v : 0.2f * v; }
__device__ __forceinline__ float elu(float v) { return v > 0.f ? v : expm1f(v); }

__device__ __forceinline__ void gload16(const u16* g, u16* l) {
    __builtin_amdgcn_global_load_lds((const __attribute__((address_space(1))) void*)(const void*)g,
                                     (__attribute__((address_space(3))) void*)(void*)l, 16, 0, 0);
}

// ---------------- k_pre: x-cast + deg-zero + detect + both weight transposes ----------------
__global__ void k_pre(const float* __restrict__ x, u16* __restrict__ xb,
                      const float* __restrict__ W1, u16* __restrict__ w1t,
                      const float* __restrict__ W2, u16* __restrict__ w2t,
                      const int* __restrict__ ei, int* __restrict__ flag,
                      int* __restrict__ deg, size_t n4, int E0, int N) {
    int bid = blockIdx.x, t = threadIdx.x;
    if (bid < 2048) {
        size_t i = (size_t)bid * 256 + t;
        const size_t stride = (size_t)2048 * 256;
        for (size_t k = i; k < n4; k += stride) {
            float4 v = ((const float4*)x)[k];
            ushort4 o;
            o.x = f2b(v.x); o.y = f2b(v.y); o.z = f2b(v.z); o.w = f2b(v.w);
            ((ushort4*)xb)[k] = o;
        }
        for (size_t k = i; k < (size_t)N; k += stride) deg[k] = 0;
        if (bid == 0) {
            if (t == 0) *flag = 0;
            __syncthreads();
            int lim = E0 < 4096 ? E0 : 4096;
            int any = 0;
            for (int k = t; k < lim; k += 256) any |= (ei[2 * k + 1] != 0);
            if (any) atomicOr(flag, 1);
        }
    } else {
        __shared__ float tile[32][33];
        int b = bid - 2048;
        const float* in; u16* outp; int R, C, cx, ry;
        if (b < 768) { in = W1; outp = w1t; R = 768; C = 1024; cx = b & 31; ry = b >> 5; }
        else { int b2 = b - 768; in = W2; outp = w2t; R = 1024; C = 128; cx = b2 & 3; ry = b2 >> 2; }
        int tx = t & 31, ty = t >> 5;
        int c0 = cx * 32, r0 = ry * 32;
        #pragma unroll
        for (int i = 0; i < 32; i += 8)
            tile[ty + i][tx] = in[(size_t)(r0 + ty + i) * C + c0 + tx];
        __syncthreads();
        #pragma unroll
        for (int i = 0; i < 32; i += 8)
            outp[(size_t)(c0 + ty + i) * R + r0 + tx] = f2b(tile[tx][ty + i]);
    }
}

// ---------------- GEMM1: C[M,NN] = A[M,K] * Bt[NN,K]^T (bf16), gload_lds + swizzle ----------
#define GBM 128
#define GBN 128
#define GBK 64
#define LDT 72
#define SPLITK 4

__global__ __launch_bounds__(256) void k_gemm(const u16* __restrict__ A, const u16* __restrict__ Bt,
                                              u16* __restrict__ C, int M, int NN, int K, int nCB) {
    __shared__ __align__(16) u16 As[GBM][GBK];
    __shared__ __align__(16) u16 Bs[GBN][GBK];
    int nwg = gridDim.x, orig = blockIdx.x;
    int q = nwg >> 3, r8 = nwg & 7, xcd = orig & 7, sub = orig >> 3;
    int wgid = (xcd < r8 ? xcd * (q + 1) : r8 * (q + 1) + (xcd - r8) * q) + sub;
    int rb = wgid / nCB, cb = wgid % nCB;
    int brow = rb * GBM, bcol = cb * GBN;

    int t = threadIdx.x, lane = t & 63, wid = t >> 6;
    int wm = (wid >> 1) * 64, wn = (wid & 1) * 64;
    int fr = lane & 15, fq = lane >> 4;
    f32x4 acc[4][4] = {};
    int srow = lane >> 3;
    int scol = (((lane & 7) ^ srow)) * 8;
    int dcol = (lane & 7) * 8;
    int nK = K / GBK;
    for (int kt = 0; kt < nK; ++kt) {
        int k0 = kt * GBK;
        #pragma unroll
        for (int cc = 0; cc < 8; ++cc) {
            int c = wid * 8 + cc;
            int r = (c & 15) * 8 + srow;
            if (c < 16) gload16(A + (size_t)(brow + r) * K + k0 + scol, &As[r][dcol]);
            else        gload16(Bt + (size_t)(bcol + r) * K + k0 + scol, &Bs[r][dcol]);
        }
        __syncthreads();
        #pragma unroll
        for (int kk = 0; kk < 2; ++kk) {
            int ko = kk * 32 + fq * 8;
            int kos = ko ^ ((fr & 7) << 3);
            bf16x8 af[4], bg[4];
            #pragma unroll
            for (int i = 0; i < 4; ++i) {
                af[i] = *reinterpret_cast<const bf16x8*>(&As[wm + i * 16 + fr][kos]);
                bg[i] = *reinterpret_cast<const bf16x8*>(&Bs[wn + i * 16 + fr][kos]);
            }
            #pragma unroll
            for (int mi = 0; mi < 4; ++mi)
                #pragma unroll
                for (int ni = 0; ni < 4; ++ni)
                    acc[mi][ni] = __builtin_amdgcn_mfma_f32_16x16x32_bf16(af[mi], bg[ni], acc[mi][ni], 0, 0, 0);
        }
        __syncthreads();
    }
    #pragma unroll
    for (int mi = 0; mi < 4; ++mi) {
        #pragma unroll
        for (int j = 0; j < 4; ++j) {
            int row = brow + wm + mi * 16 + fq * 4 + j;
            if (row < M) {
                #pragma unroll
                for (int ni = 0; ni < 4; ++ni) {
                    int col = bcol + wn + ni * 16 + fr;
                    C[(size_t)row * NN + col] = f2b(acc[mi][ni][j]);
                }
            }
        }
    }
}

// ---------------- GEMM2 split-K: partial[ks][M][128] f32, BN1+ELU fused on A-staging ----------
__global__ __launch_bounds__(256) void k_gemm2(const u16* __restrict__ A, const u16* __restrict__ Bt,
                                               float* __restrict__ Cp, int M, int K,
                                               const float* __restrict__ scA, const float* __restrict__ shA) {
    __shared__ __align__(16) u16 As[GBM][LDT];
    __shared__ __align__(16) u16 Bs[GBN][LDT];
    int brow = blockIdx.x * GBM;
    int ks = blockIdx.y;
    int kBase = ks * (K / SPLITK);
    int t = threadIdx.x;
    int lane = t & 63, wid = t >> 6;
    int wm = (wid >> 1) * 64, wn = (wid & 1) * 64;
    int fr = lane & 15, fq = lane >> 4;
    f32x4 acc[4][4] = {};
    int tr = t >> 3, tc = (t & 7) * 8;
    const int nK = 1024 / SPLITK / GBK;  // 4
    for (int kt = 0; kt < nK; ++kt) {
        int k0 = kBase + kt * GBK;
        #pragma unroll
        for (int rr = 0; rr < 4; ++rr) {
            int r = tr + rr * 32;
            int grow = brow + r;
            uint4 bv = *reinterpret_cast<const uint4*>(Bt + (size_t)r * K + k0 + tc);
            *reinterpret_cast<uint4*>(&Bs[r][tc]) = bv;
            uint4 av = make_uint4(0, 0, 0, 0);
            if (grow < M) {
                uint4 u = *reinterpret_cast<const uint4*>(A + (size_t)grow * K + k0 + tc);
                float4 s0 = *(const float4*)(scA + k0 + tc);
                float4 s1 = *(const float4*)(scA + k0 + tc + 4);
                float4 h0 = *(const float4*)(shA + k0 + tc);
                float4 h1 = *(const float4*)(shA + k0 + tc + 4);
                u16 w0 = f2b(elu(b2f((u16)(u.x & 0xffff)) * s0.x + h0.x));
                u16 w1 = f2b(elu(b2f((u16)(u.x >> 16))    * s0.y + h0.y));
                u16 w2 = f2b(elu(b2f((u16)(u.y & 0xffff)) * s0.z + h0.z));
                u16 w3 = f2b(elu(b2f((u16)(u.y >> 16))    * s0.w + h0.w));
                u16 w4 = f2b(elu(b2f((u16)(u.z & 0xffff)) * s1.x + h1.x));
                u16 w5 = f2b(elu(b2f((u16)(u.z >> 16))    * s1.y + h1.y));
                u16 w6 = f2b(elu(b2f((u16)(u.w & 0xffff)) * s1.z + h1.z));
                u16 w7 = f2b(elu(b2f((u16)(u.w >> 16))    * s1.w + h1.w));
                av.x = (unsigned)w0 | ((unsigned)w1 << 16);
                av.y = (unsigned)w2 | ((unsigned)w3 << 16);
                av.z = (unsigned)w4 | ((unsigned)w5 << 16);
                av.w = (unsigned)w6 | ((unsigned)w7 << 16);
            }
            *reinterpret_cast<uint4*>(&As[r][tc]) = av;
        }
        __syncthreads();
        #pragma unroll
        for (int kk = 0; kk < 2; ++kk) {
            int ko = kk * 32 + fq * 8;
            bf16x8 af[4], bg[4];
            #pragma unroll
            for (int i = 0; i < 4; ++i) {
                af[i] = *reinterpret_cast<const bf16x8*>(&As[wm + i * 16 + fr][ko]);
                bg[i] = *reinterpret_cast<const bf16x8*>(&Bs[wn + i * 16 + fr][ko]);
            }
            #pragma unroll
            for (int mi = 0; mi < 4; ++mi)
                #pragma unroll
                for (int ni = 0; ni < 4; ++ni)
                    acc[mi][ni] = __builtin_amdgcn_mfma_f32_16x16x32_bf16(af[mi], bg[ni], acc[mi][ni], 0, 0, 0);
        }
        __syncthreads();
    }
    float* base = Cp + (size_t)ks * M * 128;
    #pragma unroll
    for (int mi = 0; mi < 4; ++mi) {
        #pragma unroll
        for (int j = 0; j < 4; ++j) {
            int row = brow + wm + mi * 16 + fq * 4 + j;
            if (row < M) {
                #pragma unroll
                for (int ni = 0; ni < 4; ++ni) {
                    int col = wn + ni * 16 + fr;
                    base[(size_t)row * 128 + col] = acc[mi][ni][j];
                }
            }
        }
    }
}

// ---------------- reduce split-K partials -> bf16 h2 + fused att1 dots ----------------
__global__ __launch_bounds__(256) void k_red2(const float* __restrict__ Cp,
                                              const float* __restrict__ attS, const float* __restrict__ attD,
                                              u16* __restrict__ h2b, float* __restrict__ asrc,
                                              float* __restrict__ adst, int M) {
    int t = threadIdx.x, lane = t & 63, wid = t >> 6;
    int row = blockIdx.x * 4 + wid;
    if (row >= M) return;
    int c = lane * 2;
    float s0 = 0.f, s1 = 0.f;
    #pragma unroll
    for (int s = 0; s < SPLITK; ++s) {
        float2 v = *(const float2*)(Cp + ((size_t)s * M + row) * 128 + c);
        s0 += v.x; s1 += v.y;
    }
    ushort2 o; o.x = f2b(s0); o.y = f2b(s1);
    *(ushort2*)(h2b + (size_t)row * 128 + c) = o;
    float ps = s0 * attS[c] + s1 * attS[c + 1];
    float pd = s0 * attD[c] + s1 * attD[c + 1];
    #pragma unroll
    for (int m = 1; m < 64; m <<= 1) { ps += __shfl_xor(ps, m); pd += __shfl_xor(pd, m); }
    if (lane == 0) { asrc[row] = ps; adst[row] = pd; }
}

// ---------------- attention dots (layer 1) ----------------
__global__ void k_att8(const u16* __restrict__ h, const float* __restrict__ attS,
                       const float* __restrict__ attD, float* __restrict__ asrc,
                       float* __restrict__ adst, int N) {
    int t = threadIdx.x;
    int half = t >> 7, i = t & 127;
    int row = blockIdx.x * 2 + half;
    if (row >= N) return;
    int head = i >> 4, g = i & 15;
    const u16* hp = h + (size_t)row * 1024 + head * 128 + g * 8;
    const float* sp = attS + head * 128 + g * 8;
    const float* dp = attD + head * 128 + g * 8;
    ushort4 u0 = *(const ushort4*)hp;
    ushort4 u1 = *(const ushort4*)(hp + 4);
    float hv[8] = {b2f(u0.x), b2f(u0.y), b2f(u0.z), b2f(u0.w),
                   b2f(u1.x), b2f(u1.y), b2f(u1.z), b2f(u1.w)};
    float ps = 0.f, pd = 0.f;
    #pragma unroll
    for (int j = 0; j < 8; ++j) { ps += hv[j] * sp[j]; pd += hv[j] * dp[j]; }
    #pragma unroll
    for (int m = 1; m < 16; m <<= 1) { ps += __shfl_xor(ps, m); pd += __shfl_xor(pd, m); }
    if (g == 0) { asrc[row * 8 + head] = ps; adst[row * 8 + head] = pd; }
}

// ---------------- CSR build (regular kernels) ----------------
__global__ void k_deg(const int* __restrict__ ei, const int* __restrict__ flag,
                      int* __restrict__ deg, int E0, int E) {
    bool i64 = (*flag == 0);
    for (int e = blockIdx.x * blockDim.x + threadIdx.x; e < E; e += gridDim.x * blockDim.x) {
        int d;
        if (e < E0) d = i64 ? ei[2 * (E0 + e)] : ei[E0 + e];
        else d = e - E0;
        atomicAdd(&deg[d], 1);
    }
}

__global__ __launch_bounds__(1024) void k_scan(const int* __restrict__ deg, int* __restrict__ off,
                                               int* __restrict__ cursor, int n) {
    __shared__ int part[1024];
    int t = threadIdx.x;
    int chunk = (n + 1023) >> 10;
    int beg = t * chunk, end = beg + chunk;
    if (end > n) end = n;
    int s = 0;
    for (int i = beg; i < end; ++i) s += deg[i];
    part[t] = s;
    __syncthreads();
    for (int d = 1; d < 1024; d <<= 1) {
        int v = (t >= d) ? part[t - d] : 0;
        __syncthreads();
        part[t] += v;
        __syncthreads();
    }
    int run = (t == 0) ? 0 : part[t - 1];
    for (int i = beg; i < end; ++i) { off[i] = run; cursor[i] = run; run += deg[i]; }
    if (t == 1023) off[n] = part[1023];
}

__global__ void k_scatter(const int* __restrict__ ei, const int* __restrict__ flag,
                          int* __restrict__ cursor, int* __restrict__ csr, int E0, int E) {
    bool i64 = (*flag == 0);
    for (int e = blockIdx.x * blockDim.x + threadIdx.x; e < E; e += gridDim.x * blockDim.x) {
        int s, d;
        if (e < E0) {
            if (i64) { s = ei[2 * e]; d = ei[2 * (E0 + e)]; }
            else     { s = ei[e];     d = ei[E0 + e]; }
        } else { s = d = e - E0; }
        int pos = atomicAdd(&cursor[d], 1);
        csr[pos] = s;
    }
}

// ---------------- layer-1 aggregation with wave0-computed softmax in LDS ----------------
__global__ __launch_bounds__(256) void k_agg1(const int* __restrict__ off, const int* __restrict__ csr,
                                              const float* __restrict__ asrc, const float* __restrict__ adst,
                                              const u16* __restrict__ h1, u16* __restrict__ outg, int N) {
    __shared__ float pch[64][8];
    __shared__ float invs[8];
    int node = blockIdx.x;
    if (node >= N) return;
    int t = threadIdx.x, lane = t & 63, wid = t >> 6;
    int hh = t >> 5;
    int c0 = t * 4;
    int lo = off[node], hi = off[node + 1];
    float ad_l = 0.f, mmax = -1e30f, ssum = 0.f;
    int h = lane & 7, es = lane >> 3;
    if (wid == 0) {
        ad_l = adst[(size_t)node * 8 + h];
        for (int i = lo + es; i < hi; i += 8)
            mmax = fmaxf(mmax, leaky(asrc[(size_t)csr[i] * 8 + h] + ad_l));
        #pragma unroll
        for (int mask = 8; mask < 64; mask <<= 1) mmax = fmaxf(mmax, __shfl_xor(mmax, mask));
    }
    float a0 = 0.f, a1 = 0.f, a2 = 0.f, a3 = 0.f;
    for (int base = lo; base < hi; base += 64) {
        int cend = base + 64 < hi ? base + 64 : hi;
        if (wid == 0) {
            for (int i = base + es; i < cend; i += 8) {
                float p = __expf(leaky(asrc[(size_t)csr[i] * 8 + h] + ad_l) - mmax);
                pch[i - base][h] = p;
                ssum += p;
            }
        }
        __syncthreads();
        for (int i = base; i < cend; ++i) {
            float p = pch[i - base][hh];
            ushort4 u = *(const ushort4*)(h1 + (size_t)csr[i] * 1024 + c0);
            a0 += p * b2f(u.x); a1 += p * b2f(u.y);
            a2 += p * b2f(u.z); a3 += p * b2f(u.w);
        }
        __syncthreads();
    }
    if (wid == 0) {
        #pragma unroll
        for (int mask = 8; mask < 64; mask <<= 1) ssum += __shfl_xor(ssum, mask);
        if (lane < 8) invs[lane] = 1.f / (ssum + 1e-16f);
    }
    __syncthreads();
    float inv = invs[hh];
    ushort4 o;
    o.x = f2b(a0 * inv); o.y = f2b(a1 * inv); o.z = f2b(a2 * inv); o.w = f2b(a3 * inv);
    *(ushort4*)(outg + (size_t)node * 1024 + c0) = o;
}

// ---------------- layer-2 aggregation with fused softmax (128 threads = 1 node) ----------------
__global__ __launch_bounds__(128) void k_agg2(const int* __restrict__ off, const int* __restrict__ csr,
                                              const float* __restrict__ asrc, const float* __restrict__ adst,
                                              const u16* __restrict__ h2, u16* __restrict__ outg, int N) {
    __shared__ float pch[64];
    __shared__ float invsh;
    int node = blockIdx.x;
    if (node >= N) return;
    int t = threadIdx.x, lane = t & 63, wid = t >> 6;
    int lo = off[node], hi = off[node + 1];
    float ad = adst[node];
    float mmax = -1e30f, ssum = 0.f;
    if (wid == 0) {
        for (int i = lo + lane; i < hi; i += 64)
            mmax = fmaxf(mmax, leaky(asrc[csr[i]] + ad));
        #pragma unroll
        for (int mask = 1; mask < 64; mask <<= 1) mmax = fmaxf(mmax, __shfl_xor(mmax, mask));
    }
    float acc = 0.f;
    for (int base = lo; base < hi; base += 64) {
        int cend = base + 64 < hi ? base + 64 : hi;
        if (wid == 0 && base + lane < cend) {
            float p = __expf(leaky(asrc[csr[base + lane]] + ad) - mmax);
            pch[lane] = p;
            ssum += p;
        }
        __syncthreads();
        for (int i = base; i < cend; ++i)
            acc += pch[i - base] * b2f(h2[(size_t)csr[i] * 128 + t]);
        __syncthreads();
    }
    if (wid == 0) {
        #pragma unroll
        for (int mask = 1; mask < 64; mask <<= 1) ssum += __shfl_xor(ssum, mask);
        if (lane == 0) invsh = 1.f / (ssum + 1e-16f);
    }
    __syncthreads();
    outg[(size_t)node * 128 + t] = f2b(acc * invsh);
}

// ---------------- batchnorm: two-stage reduction (regular kernels) ----------------
template <int CH>
__global__ __launch_bounds__(256) void k_bnpart(const u16* __restrict__ g, float* __restrict__ ps,
                                                float* __restrict__ ps2, int Nrows, int rowsPerChunk) {
    const int TPR = CH / 4;
    const int RPI = 256 / TPR;
    int t = threadIdx.x;
    int rl = t / TPR, c4 = (t % TPR) * 4;
    int chunk = blockIdx.x;
    int r0 = chunk * rowsPerChunk;
    int r1 = r0 + rowsPerChunk; if (r1 > Nrows) r1 = Nrows;
    float s[4] = {0.f, 0.f, 0.f, 0.f}, s2[4] = {0.f, 0.f, 0.f, 0.f};
    for (int r = r0 + rl; r < r1; r += RPI) {
        ushort4 u = *(const ushort4*)(g + (size_t)r * CH + c4);
        float v0 = b2f(u.x), v1 = b2f(u.y), v2 = b2f(u.z), v3 = b2f(u.w);
        s[0] += v0; s2[0] += v0 * v0;
        s[1] += v1; s2[1] += v1 * v1;
        s[2] += v2; s2[2] += v2 * v2;
        s[3] += v3; s2[3] += v3 * v3;
    }
    size_t prow = (size_t)(chunk * RPI + rl) * CH + c4;
    *(float4*)(ps + prow)  = make_float4(s[0], s[1], s[2], s[3]);
    *(float4*)(ps2 + prow) = make_float4(s2[0], s2[1], s2[2], s2[3]);
}

__global__ __launch_bounds__(256) void k_bnfinal(const float* __restrict__ ps, const float* __restrict__ ps2,
                                                 const float* __restrict__ gamma, const float* __restrict__ beta,
                                                 float* __restrict__ scale, float* __restrict__ shift,
                                                 int P, int CH, int Nrows) {
    int t = threadIdx.x, lane = t & 63, wid = t >> 6;
    int col = blockIdx.x * 4 + wid;
    if (col >= CH) return;
    float s = 0.f, s2 = 0.f;
    for (int p = lane; p < P; p += 64) {
        s += ps[(size_t)p * CH + col];
        s2 += ps2[(size_t)p * CH + col];
    }
    #pragma unroll
    for (int m = 1; m < 64; m <<= 1) { s += __shfl_xor(s, m); s2 += __shfl_xor(s2, m); }
    if (lane == 0) {
        double mu = (double)s / Nrows;
        double var = (double)s2 / Nrows - mu * mu;
        if (var < 0) var = 0;
        float sc = gamma[col] * rsqrtf((float)var + 1e-5f);
        scale[col] = sc;
        shift[col] = beta[col] - (float)mu * sc;
    }
}

// ---------------- classifier (fused BN2+ELU on load, 64 rows/block) ----------------
__global__ __launch_bounds__(256) void k_cls(const u16* __restrict__ g2raw,
                                             const float* __restrict__ scale2, const float* __restrict__ shift2,
                                             const float* __restrict__ Wc1, const float* __restrict__ bc1,
                                             const float* __restrict__ Wc2, const float* __restrict__ bc2,
                                             float* __restrict__ out, int N) {
    __shared__ float wl[128 * 64];
    __shared__ float hs[4][128];
    int t = threadIdx.x, lane = t & 63, wid = t >> 6;
    for (int i = t; i < 128 * 64; i += 256) wl[i] = Wc1[i];
    float sc0 = scale2[2 * lane], sc1 = scale2[2 * lane + 1];
    float sh0 = shift2[2 * lane], sh1 = shift2[2 * lane + 1];
    float bb = bc1[lane];
    float c2a = Wc2[lane * 2], c2b = Wc2[lane * 2 + 1];
    float o2a = bc2[0], o2b = bc2[1];
    __syncthreads();
    int row0 = blockIdx.x * 64;
    for (int it = 0; it < 16; ++it) {
        int row = row0 + it * 4 + wid;
        if (row >= N) continue;
        const u16* hp = g2raw + (size_t)row * 128 + 2 * lane;
        float y0 = b2f(hp[0]) * sc0 + sh0; y0 = y0 > 0.f ? y0 : expm1f(y0);
        float y1 = b2f(hp[1]) * sc1 + sh1; y1 = y1 > 0.f ? y1 : expm1f(y1);
        hs[wid][2 * lane] = y0;
        hs[wid][2 * lane + 1] = y1;
        float tj = bb;
        #pragma unroll 8
        for (int c = 0; c < 128; ++c) tj += hs[wid][c] * wl[c * 64 + lane];
        tj = tj > 0.f ? tj : expm1f(tj);
        float v0 = tj * c2a, v1 = tj * c2b;
        #pragma unroll
        for (int m = 1; m < 64; m <<= 1) { v0 += __shfl_xor(v0, m); v1 += __shfl_xor(v1, m); }
        if (lane == 0) {
            out[(size_t)row * 2 + 0] = v0 + o2a;
            out[(size_t)row * 2 + 1] = v1 + o2b;
        }
    }
}

// ---------------- host launch ----------------
extern "C" void kernel_launch(void* const* d_in, const int* in_sizes, int n_in,
                              void* d_out, int out_size, void* d_ws, size_t ws_size,
                              hipStream_t stream) {
    const float* x     = (const float*)d_in[0];
    const int*   ei    = (const int*)d_in[1];
    const float* W1    = (const float*)d_in[2];
    const float* attS1 = (const float*)d_in[3];
    const float* attD1 = (const float*)d_in[4];
    const float* bn1g  = (const float*)d_in[6];
    const float* bn1b  = (const float*)d_in[7];
    const float* W2    = (const float*)d_in[8];
    const float* attS2 = (const float*)d_in[9];
    const float* attD2 = (const float*)d_in[10];
    const float* bn2g  = (const float*)d_in[12];
    const float* bn2b  = (const float*)d_in[13];
    const float* Wc1   = (const float*)d_in[14];
    const float* bc1   = (const float*)d_in[15];
    const float* Wc2   = (const float*)d_in[16];
    const float* bc2   = (const float*)d_in[17];
    float* out = (float*)d_out;

    const int DIN = 768, F1 = 1024, C2 = 128;
    int N = in_sizes[0] / DIN;                  // 20000
    int E0 = in_sizes[1] / 2;                   // 160000
    int E = E0 + N;
    const int nMB = (N + GBM - 1) / GBM;        // 157 row-blocks
    const int Mp = nMB * GBM;                   // 20096 padded rows

    char* w = (char*)d_ws;
    auto take = [&](size_t bytes) -> void* {
        void* p = (void*)w;
        w += (bytes + 255) & ~(size_t)255;
        return p;
    };
    u16* xb     = (u16*)take((size_t)Mp * DIN * 2);
    u16* bufA   = (u16*)take((size_t)N * F1 * 2);
    u16* h1b    = (u16*)take((size_t)N * F1 * 2);
    u16* w1t    = (u16*)take((size_t)F1 * DIN * 2);
    u16* w2t    = (u16*)take((size_t)C2 * F1 * 2);
    float* asrc1 = (float*)take((size_t)N * 8 * 4);
    float* adst1 = (float*)take((size_t)N * 8 * 4);
    int* deg    = (int*)take((size_t)N * 4);
    int* off    = (int*)take((size_t)(N + 1) * 4);
    int* cursor = (int*)take((size_t)N * 4);
    int* csr    = (int*)take((size_t)E * 4);
    int* flag   = (int*)take(256);
    u16* h2b    = (u16*)take((size_t)N * C2 * 2);
    float* asrc2 = (float*)take((size_t)N * 4);
    float* adst2 = (float*)take((size_t)N * 4);
    u16* g2     = (u16*)take((size_t)N * C2 * 2);
    float* scale1 = (float*)take(F1 * 4);
    float* shift1 = (float*)take(F1 * 4);
    float* scale2 = (float*)take(C2 * 4);
    float* shift2 = (float*)take(C2 * 4);
    float* psA   = (float*)take((size_t)1024 * 1024 * 4);
    float* psB   = (float*)take((size_t)1024 * 1024 * 4);
    float* part  = (float*)h1b;  // split-K partials alias h1b (dead after k_agg1)

    size_t n4 = (size_t)N * DIN / 4;

    // 1. pre: cast + deg-zero + detect + weight transposes (merged, regular launch)
    k_pre<<<2048 + 896, 256, 0, stream>>>(x, xb, W1, w1t, W2, w2t, ei, flag, deg, n4, E0, N);

    // 2. layer 1 GEMM + att dots
    k_gemm<<<nMB * (F1 / GBN), 256, 0, stream>>>(xb, w1t, h1b, N, F1, DIN, F1 / GBN);
    k_att8<<<(N + 1) / 2, 256, 0, stream>>>(h1b, attS1, attD1, asrc1, adst1, N);

    // 3. CSR by destination (regular kernels)
    k_deg<<<512, 256, 0, stream>>>(ei, flag, deg, E0, E);
    k_scan<<<1, 1024, 0, stream>>>(deg, off, cursor, N);
    k_scatter<<<512, 256, 0, stream>>>(ei, flag, cursor, csr, E0, E);

    // 4. layer 1: fused softmax+gather -> BN stats
    k_agg1<<<N, 256, 0, stream>>>(off, csr, asrc1, adst1, h1b, bufA, N);
    {
        int nchunk = 256, rpc = (N + nchunk - 1) / nchunk;
        k_bnpart<1024><<<nchunk, 256, 0, stream>>>(bufA, psA, psB, N, rpc);
        k_bnfinal<<<F1 / 4, 256, 0, stream>>>(psA, psB, bn1g, bn1b, scale1, shift1, nchunk, F1, N);
    }

    // 5. layer 2 GEMM (split-K, BN1+ELU fused) + reduce + att dots
    k_gemm2<<<dim3(nMB, SPLITK), 256, 0, stream>>>(bufA, w2t, part, N, F1, scale1, shift1);
    k_red2<<<(N + 3) / 4, 256, 0, stream>>>(part, attS2, attD2, h2b, asrc2, adst2, N);

    // 6. layer 2: fused softmax+gather -> BN stats
    k_agg2<<<N, 128, 0, stream>>>(off, csr, asrc2, adst2, h2b, g2, N);
    {
        int nchunk = 128, rpc = (N + nchunk - 1) / nchunk;
        k_bnpart<128><<<nchunk, 256, 0, stream>>>(g2, psA, psB, N, rpc);
        k_bnfinal<<<C2 / 4, 256, 0, stream>>>(psA, psB, bn2g, bn2b, scale2, shift2, nchunk * 8, C2, N);
    }

    // 7. classifier head (fused BN2+ELU)
    k_cls<<<(N + 63) / 64, 256, 0, stream>>>(g2, scale2, shift2, Wc1, bc1, Wc2, bc2, out, N);
}

// Round 14
// 337.390 us; speedup vs baseline: 1.2831x; 1.0098x over previous
//
#include <hip/hip_runtime.h>
#include <stdint.h>

typedef unsigned short u16;
typedef __bf16 bf16x8 __attribute__((ext_vector_type(8)));
typedef float f32x4 __attribute__((ext_vector_type(4)));

__device__ __forceinline__ float b2f(u16 u) {
    unsigned x = ((unsigned)u) << 16;
    return __builtin_bit_cast(float, x);
}
__device__ __forceinline__ u16 f2b(float f) {
    unsigned x = __builtin_bit_cast(unsigned, f);
    x = x + 0x7fffu + ((x >> 16) & 1u);
    return (u16)(x >> 16);
}
__device__ __forceinline__ float leaky(float v) { return v > 0.f ? v : 0.2f * v; }
__device__ __forceinline__ float elu(float v) { return v > 0.f ? v : expm1f(v); }

__device__ __forceinline__ void gload16(const u16* g, u16* l) {
    __builtin_amdgcn_global_load_lds((const __attribute__((address_space(1))) void*)(const void*)g,
                                     (__attribute__((address_space(3))) void*)(void*)l, 16, 0, 0);
}

// ---------------- k_pre: x-cast + deg-zero + detect + both weight transposes ----------------
__global__ void k_pre(const float* __restrict__ x, u16* __restrict__ xb,
                      const float* __restrict__ W1, u16* __restrict__ w1t,
                      const float* __restrict__ W2, u16* __restrict__ w2t,
                      const int* __restrict__ ei, int* __restrict__ flag,
                      int* __restrict__ deg, size_t n4, int E0, int N) {
    int bid = blockIdx.x, t = threadIdx.x;
    if (bid < 2048) {
        size_t i = (size_t)bid * 256 + t;
        const size_t stride = (size_t)2048 * 256;
        for (size_t k = i; k < n4; k += stride) {
            float4 v = ((const float4*)x)[k];
            ushort4 o;
            o.x = f2b(v.x); o.y = f2b(v.y); o.z = f2b(v.z); o.w = f2b(v.w);
            ((ushort4*)xb)[k] = o;
        }
        for (size_t k = i; k < (size_t)N; k += stride) deg[k] = 0;
        if (bid == 0) {
            if (t == 0) *flag = 0;
            __syncthreads();
            int lim = E0 < 4096 ? E0 : 4096;
            int any = 0;
            for (int k = t; k < lim; k += 256) any |= (ei[2 * k + 1] != 0);
            if (any) atomicOr(flag, 1);
        }
    } else {
        __shared__ float tile[32][33];
        int b = bid - 2048;
        const float* in; u16* outp; int R, C, cx, ry;
        if (b < 768) { in = W1; outp = w1t; R = 768; C = 1024; cx = b & 31; ry = b >> 5; }
        else { int b2 = b - 768; in = W2; outp = w2t; R = 1024; C = 128; cx = b2 & 3; ry = b2 >> 2; }
        int tx = t & 31, ty = t >> 5;
        int c0 = cx * 32, r0 = ry * 32;
        #pragma unroll
        for (int i = 0; i < 32; i += 8)
            tile[ty + i][tx] = in[(size_t)(r0 + ty + i) * C + c0 + tx];
        __syncthreads();
        #pragma unroll
        for (int i = 0; i < 32; i += 8)
            outp[(size_t)(c0 + ty + i) * R + r0 + tx] = f2b(tile[tx][ty + i]);
    }
}

// ---------------- GEMM1: C[M,NN] = A[M,K] * Bt[NN,K]^T (bf16), gload_lds + swizzle ----------
#define GBM 128
#define GBN 128
#define GBK 64
#define LDT 72
#define SPLITK 4

__global__ __launch_bounds__(256) void k_gemm(const u16* __restrict__ A, const u16* __restrict__ Bt,
                                              u16* __restrict__ C, int M, int NN, int K, int nCB) {
    __shared__ __align__(16) u16 As[GBM][GBK];
    __shared__ __align__(16) u16 Bs[GBN][GBK];
    int nwg = gridDim.x, orig = blockIdx.x;
    int q = nwg >> 3, r8 = nwg & 7, xcd = orig & 7, sub = orig >> 3;
    int wgid = (xcd < r8 ? xcd * (q + 1) : r8 * (q + 1) + (xcd - r8) * q) + sub;
    int rb = wgid / nCB, cb = wgid % nCB;
    int brow = rb * GBM, bcol = cb * GBN;

    int t = threadIdx.x, lane = t & 63, wid = t >> 6;
    int wm = (wid >> 1) * 64, wn = (wid & 1) * 64;
    int fr = lane & 15, fq = lane >> 4;
    f32x4 acc[4][4] = {};
    int srow = lane >> 3;
    int scol = (((lane & 7) ^ srow)) * 8;
    int dcol = (lane & 7) * 8;
    int nK = K / GBK;
    for (int kt = 0; kt < nK; ++kt) {
        int k0 = kt * GBK;
        #pragma unroll
        for (int cc = 0; cc < 8; ++cc) {
            int c = wid * 8 + cc;
            int r = (c & 15) * 8 + srow;
            if (c < 16) gload16(A + (size_t)(brow + r) * K + k0 + scol, &As[r][dcol]);
            else        gload16(Bt + (size_t)(bcol + r) * K + k0 + scol, &Bs[r][dcol]);
        }
        __syncthreads();
        #pragma unroll
        for (int kk = 0; kk < 2; ++kk) {
            int ko = kk * 32 + fq * 8;
            int kos = ko ^ ((fr & 7) << 3);
            bf16x8 af[4], bg[4];
            #pragma unroll
            for (int i = 0; i < 4; ++i) {
                af[i] = *reinterpret_cast<const bf16x8*>(&As[wm + i * 16 + fr][kos]);
                bg[i] = *reinterpret_cast<const bf16x8*>(&Bs[wn + i * 16 + fr][kos]);
            }
            #pragma unroll
            for (int mi = 0; mi < 4; ++mi)
                #pragma unroll
                for (int ni = 0; ni < 4; ++ni)
                    acc[mi][ni] = __builtin_amdgcn_mfma_f32_16x16x32_bf16(af[mi], bg[ni], acc[mi][ni], 0, 0, 0);
        }
        __syncthreads();
    }
    #pragma unroll
    for (int mi = 0; mi < 4; ++mi) {
        #pragma unroll
        for (int j = 0; j < 4; ++j) {
            int row = brow + wm + mi * 16 + fq * 4 + j;
            if (row < M) {
                #pragma unroll
                for (int ni = 0; ni < 4; ++ni) {
                    int col = bcol + wn + ni * 16 + fr;
                    C[(size_t)row * NN + col] = f2b(acc[mi][ni][j]);
                }
            }
        }
    }
}

// ---------------- GEMM2 split-K: partial[ks][M][128] f32, BN1+ELU fused on A-staging ----------
__global__ __launch_bounds__(256) void k_gemm2(const u16* __restrict__ A, const u16* __restrict__ Bt,
                                               float* __restrict__ Cp, int M, int K,
                                               const float* __restrict__ scA, const float* __restrict__ shA) {
    __shared__ __align__(16) u16 As[GBM][LDT];
    __shared__ __align__(16) u16 Bs[GBN][LDT];
    int brow = blockIdx.x * GBM;
    int ks = blockIdx.y;
    int kBase = ks * (K / SPLITK);
    int t = threadIdx.x;
    int lane = t & 63, wid = t >> 6;
    int wm = (wid >> 1) * 64, wn = (wid & 1) * 64;
    int fr = lane & 15, fq = lane >> 4;
    f32x4 acc[4][4] = {};
    int tr = t >> 3, tc = (t & 7) * 8;
    const int nK = 1024 / SPLITK / GBK;  // 4
    for (int kt = 0; kt < nK; ++kt) {
        int k0 = kBase + kt * GBK;
        #pragma unroll
        for (int rr = 0; rr < 4; ++rr) {
            int r = tr + rr * 32;
            int grow = brow + r;
            uint4 bv = *reinterpret_cast<const uint4*>(Bt + (size_t)r * K + k0 + tc);
            *reinterpret_cast<uint4*>(&Bs[r][tc]) = bv;
            uint4 av = make_uint4(0, 0, 0, 0);
            if (grow < M) {
                uint4 u = *reinterpret_cast<const uint4*>(A + (size_t)grow * K + k0 + tc);
                float4 s0 = *(const float4*)(scA + k0 + tc);
                float4 s1 = *(const float4*)(scA + k0 + tc + 4);
                float4 h0 = *(const float4*)(shA + k0 + tc);
                float4 h1 = *(const float4*)(shA + k0 + tc + 4);
                u16 w0 = f2b(elu(b2f((u16)(u.x & 0xffff)) * s0.x + h0.x));
                u16 w1 = f2b(elu(b2f((u16)(u.x >> 16))    * s0.y + h0.y));
                u16 w2 = f2b(elu(b2f((u16)(u.y & 0xffff)) * s0.z + h0.z));
                u16 w3 = f2b(elu(b2f((u16)(u.y >> 16))    * s0.w + h0.w));
                u16 w4 = f2b(elu(b2f((u16)(u.z & 0xffff)) * s1.x + h1.x));
                u16 w5 = f2b(elu(b2f((u16)(u.z >> 16))    * s1.y + h1.y));
                u16 w6 = f2b(elu(b2f((u16)(u.w & 0xffff)) * s1.z + h1.z));
                u16 w7 = f2b(elu(b2f((u16)(u.w >> 16))    * s1.w + h1.w));
                av.x = (unsigned)w0 | ((unsigned)w1 << 16);
                av.y = (unsigned)w2 | ((unsigned)w3 << 16);
                av.z = (unsigned)w4 | ((unsigned)w5 << 16);
                av.w = (unsigned)w6 | ((unsigned)w7 << 16);
            }
            *reinterpret_cast<uint4*>(&As[r][tc]) = av;
        }
        __syncthreads();
        #pragma unroll
        for (int kk = 0; kk < 2; ++kk) {
            int ko = kk * 32 + fq * 8;
            bf16x8 af[4], bg[4];
            #pragma unroll
            for (int i = 0; i < 4; ++i) {
                af[i] = *reinterpret_cast<const bf16x8*>(&As[wm + i * 16 + fr][ko]);
                bg[i] = *reinterpret_cast<const bf16x8*>(&Bs[wn + i * 16 + fr][ko]);
            }
            #pragma unroll
            for (int mi = 0; mi < 4; ++mi)
                #pragma unroll
                for (int ni = 0; ni < 4; ++ni)
                    acc[mi][ni] = __builtin_amdgcn_mfma_f32_16x16x32_bf16(af[mi], bg[ni], acc[mi][ni], 0, 0, 0);
        }
        __syncthreads();
    }
    float* base = Cp + (size_t)ks * M * 128;
    #pragma unroll
    for (int mi = 0; mi < 4; ++mi) {
        #pragma unroll
        for (int j = 0; j < 4; ++j) {
            int row = brow + wm + mi * 16 + fq * 4 + j;
            if (row < M) {
                #pragma unroll
                for (int ni = 0; ni < 4; ++ni) {
                    int col = wn + ni * 16 + fr;
                    base[(size_t)row * 128 + col] = acc[mi][ni][j];
                }
            }
        }
    }
}

// ---------------- reduce split-K partials -> bf16 h2 + fused att1 dots ----------------
__global__ __launch_bounds__(256) void k_red2(const float* __restrict__ Cp,
                                              const float* __restrict__ attS, const float* __restrict__ attD,
                                              u16* __restrict__ h2b, float* __restrict__ asrc,
                                              float* __restrict__ adst, int M) {
    int t = threadIdx.x, lane = t & 63, wid = t >> 6;
    int row = blockIdx.x * 4 + wid;
    if (row >= M) return;
    int c = lane * 2;
    float s0 = 0.f, s1 = 0.f;
    #pragma unroll
    for (int s = 0; s < SPLITK; ++s) {
        float2 v = *(const float2*)(Cp + ((size_t)s * M + row) * 128 + c);
        s0 += v.x; s1 += v.y;
    }
    ushort2 o; o.x = f2b(s0); o.y = f2b(s1);
    *(ushort2*)(h2b + (size_t)row * 128 + c) = o;
    float ps = s0 * attS[c] + s1 * attS[c + 1];
    float pd = s0 * attD[c] + s1 * attD[c + 1];
    #pragma unroll
    for (int m = 1; m < 64; m <<= 1) { ps += __shfl_xor(ps, m); pd += __shfl_xor(pd, m); }
    if (lane == 0) { asrc[row] = ps; adst[row] = pd; }
}

// ---------------- k_attdeg: layer-1 att dots (blocks < nAtt) + degree histogram (rest) ------
__global__ void k_attdeg(const u16* __restrict__ h, const float* __restrict__ attS,
                         const float* __restrict__ attD, float* __restrict__ asrc,
                         float* __restrict__ adst, const int* __restrict__ ei,
                         const int* __restrict__ flag, int* __restrict__ deg,
                         int N, int E0, int E, int nAtt) {
    int bid = blockIdx.x, t = threadIdx.x;
    if (bid < nAtt) {
        int half = t >> 7, i = t & 127;
        int row = bid * 2 + half;
        if (row >= N) return;
        int head = i >> 4, g = i & 15;
        const u16* hp = h + (size_t)row * 1024 + head * 128 + g * 8;
        const float* sp = attS + head * 128 + g * 8;
        const float* dp = attD + head * 128 + g * 8;
        ushort4 u0 = *(const ushort4*)hp;
        ushort4 u1 = *(const ushort4*)(hp + 4);
        float hv[8] = {b2f(u0.x), b2f(u0.y), b2f(u0.z), b2f(u0.w),
                       b2f(u1.x), b2f(u1.y), b2f(u1.z), b2f(u1.w)};
        float ps = 0.f, pd = 0.f;
        #pragma unroll
        for (int j = 0; j < 8; ++j) { ps += hv[j] * sp[j]; pd += hv[j] * dp[j]; }
        #pragma unroll
        for (int m = 1; m < 16; m <<= 1) { ps += __shfl_xor(ps, m); pd += __shfl_xor(pd, m); }
        if (g == 0) { asrc[row * 8 + head] = ps; adst[row * 8 + head] = pd; }
    } else {
        int b = bid - nAtt;
        bool i64 = (*flag == 0);
        for (int e = b * 256 + t; e < E; e += 512 * 256) {
            int d;
            if (e < E0) d = i64 ? ei[2 * (E0 + e)] : ei[E0 + e];
            else d = e - E0;
            atomicAdd(&deg[d], 1);
        }
    }
}

// ---------------- CSR scan + scatter ----------------
__global__ __launch_bounds__(1024) void k_scan(const int* __restrict__ deg, int* __restrict__ off,
                                               int* __restrict__ cursor, int n) {
    __shared__ int part[1024];
    int t = threadIdx.x;
    int chunk = (n + 1023) >> 10;
    int beg = t * chunk, end = beg + chunk;
    if (end > n) end = n;
    int s = 0;
    for (int i = beg; i < end; ++i) s += deg[i];
    part[t] = s;
    __syncthreads();
    for (int d = 1; d < 1024; d <<= 1) {
        int v = (t >= d) ? part[t - d] : 0;
        __syncthreads();
        part[t] += v;
        __syncthreads();
    }
    int run = (t == 0) ? 0 : part[t - 1];
    for (int i = beg; i < end; ++i) { off[i] = run; cursor[i] = run; run += deg[i]; }
    if (t == 1023) off[n] = part[1023];
}

__global__ void k_scatter(const int* __restrict__ ei, const int* __restrict__ flag,
                          int* __restrict__ cursor, int* __restrict__ csr, int E0, int E) {
    bool i64 = (*flag == 0);
    for (int e = blockIdx.x * blockDim.x + threadIdx.x; e < E; e += gridDim.x * blockDim.x) {
        int s, d;
        if (e < E0) {
            if (i64) { s = ei[2 * e]; d = ei[2 * (E0 + e)]; }
            else     { s = ei[e];     d = ei[E0 + e]; }
        } else { s = d = e - E0; }
        int pos = atomicAdd(&cursor[d], 1);
        csr[pos] = s;
    }
}

// ---------------- layer-1 aggregation: wave0 softmax + 2-edge-in-flight 16B gather ----------
__global__ __launch_bounds__(256) void k_agg1(const int* __restrict__ off, const int* __restrict__ csr,
                                              const float* __restrict__ asrc, const float* __restrict__ adst,
                                              const u16* __restrict__ h1, u16* __restrict__ outg, int N) {
    __shared__ float pch[64][8];
    __shared__ float invs[8];
    __shared__ float red[128][9];   // padded: stride 9 floats -> conflict-free
    int node = blockIdx.x;
    if (node >= N) return;
    int t = threadIdx.x, lane = t & 63, wid = t >> 6;
    int tl = t & 127, te = t >> 7;  // channel-group (8 ch each), edge parity
    int hh = tl >> 4;               // head of this channel group
    int c0 = tl * 8;
    int lo = off[node], hi = off[node + 1];
    float ad_l = 0.f, mmax = -1e30f, ssum = 0.f;
    int h = lane & 7, es = lane >> 3;
    if (wid == 0) {
        ad_l = adst[(size_t)node * 8 + h];
        for (int i = lo + es; i < hi; i += 8)
            mmax = fmaxf(mmax, leaky(asrc[(size_t)csr[i] * 8 + h] + ad_l));
        #pragma unroll
        for (int mask = 8; mask < 64; mask <<= 1) mmax = fmaxf(mmax, __shfl_xor(mmax, mask));
    }
    float a[8] = {};
    for (int base = lo; base < hi; base += 64) {
        int cend = base + 64 < hi ? base + 64 : hi;
        if (wid == 0) {
            for (int i = base + es; i < cend; i += 8) {
                float p = __expf(leaky(asrc[(size_t)csr[i] * 8 + h] + ad_l) - mmax);
                pch[i - base][h] = p;
                ssum += p;
            }
        }
        __syncthreads();
        for (int i = base + te; i < cend; i += 2) {
            float p = pch[i - base][hh];
            uint4 u = *(const uint4*)(h1 + (size_t)csr[i] * 1024 + c0);
            a[0] += p * b2f((u16)(u.x & 0xffff));
            a[1] += p * b2f((u16)(u.x >> 16));
            a[2] += p * b2f((u16)(u.y & 0xffff));
            a[3] += p * b2f((u16)(u.y >> 16));
            a[4] += p * b2f((u16)(u.z & 0xffff));
            a[5] += p * b2f((u16)(u.z >> 16));
            a[6] += p * b2f((u16)(u.w & 0xffff));
            a[7] += p * b2f((u16)(u.w >> 16));
        }
        __syncthreads();
    }
    if (wid == 0) {
        #pragma unroll
        for (int mask = 8; mask < 64; mask <<= 1) ssum += __shfl_xor(ssum, mask);
        if (lane < 8) invs[lane] = 1.f / (ssum + 1e-16f);
    }
    if (te == 1) {
        #pragma unroll
        for (int j = 0; j < 8; ++j) red[tl][j] = a[j];
    }
    __syncthreads();
    if (te == 0) {
        float inv = invs[hh];
        #pragma unroll
        for (int j = 0; j < 8; ++j) a[j] = (a[j] + red[tl][j]) * inv;
        uint4 o;
        o.x = (unsigned)f2b(a[0]) | ((unsigned)f2b(a[1]) << 16);
        o.y = (unsigned)f2b(a[2]) | ((unsigned)f2b(a[3]) << 16);
        o.z = (unsigned)f2b(a[4]) | ((unsigned)f2b(a[5]) << 16);
        o.w = (unsigned)f2b(a[6]) | ((unsigned)f2b(a[7]) << 16);
        *(uint4*)(outg + (size_t)node * 1024 + c0) = o;
    }
}

// ---------------- layer-2 aggregation with fused softmax (128 threads = 1 node) ----------------
__global__ __launch_bounds__(128) void k_agg2(const int* __restrict__ off, const int* __restrict__ csr,
                                              const float* __restrict__ asrc, const float* __restrict__ adst,
                                              const u16* __restrict__ h2, u16* __restrict__ outg, int N) {
    __shared__ float pch[64];
    __shared__ float invsh;
    int node = blockIdx.x;
    if (node >= N) return;
    int t = threadIdx.x, lane = t & 63, wid = t >> 6;
    int lo = off[node], hi = off[node + 1];
    float ad = adst[node];
    float mmax = -1e30f, ssum = 0.f;
    if (wid == 0) {
        for (int i = lo + lane; i < hi; i += 64)
            mmax = fmaxf(mmax, leaky(asrc[csr[i]] + ad));
        #pragma unroll
        for (int mask = 1; mask < 64; mask <<= 1) mmax = fmaxf(mmax, __shfl_xor(mmax, mask));
    }
    float acc = 0.f;
    for (int base = lo; base < hi; base += 64) {
        int cend = base + 64 < hi ? base + 64 : hi;
        if (wid == 0 && base + lane < cend) {
            float p = __expf(leaky(asrc[csr[base + lane]] + ad) - mmax);
            pch[lane] = p;
            ssum += p;
        }
        __syncthreads();
        for (int i = base; i < cend; ++i)
            acc += pch[i - base] * b2f(h2[(size_t)csr[i] * 128 + t]);
        __syncthreads();
    }
    if (wid == 0) {
        #pragma unroll
        for (int mask = 1; mask < 64; mask <<= 1) ssum += __shfl_xor(ssum, mask);
        if (lane == 0) invsh = 1.f / (ssum + 1e-16f);
    }
    __syncthreads();
    outg[(size_t)node * 128 + t] = f2b(acc * invsh);
}

// ---------------- batchnorm: two-stage reduction ----------------
template <int CH>
__global__ __launch_bounds__(256) void k_bnpart(const u16* __restrict__ g, float* __restrict__ ps,
                                                float* __restrict__ ps2, int Nrows, int rowsPerChunk) {
    const int TPR = CH / 4;
    const int RPI = 256 / TPR;
    int t = threadIdx.x;
    int rl = t / TPR, c4 = (t % TPR) * 4;
    int chunk = blockIdx.x;
    int r0 = chunk * rowsPerChunk;
    int r1 = r0 + rowsPerChunk; if (r1 > Nrows) r1 = Nrows;
    float s[4] = {0.f, 0.f, 0.f, 0.f}, s2[4] = {0.f, 0.f, 0.f, 0.f};
    for (int r = r0 + rl; r < r1; r += RPI) {
        ushort4 u = *(const ushort4*)(g + (size_t)r * CH + c4);
        float v0 = b2f(u.x), v1 = b2f(u.y), v2 = b2f(u.z), v3 = b2f(u.w);
        s[0] += v0; s2[0] += v0 * v0;
        s[1] += v1; s2[1] += v1 * v1;
        s[2] += v2; s2[2] += v2 * v2;
        s[3] += v3; s2[3] += v3 * v3;
    }
    size_t prow = (size_t)(chunk * RPI + rl) * CH + c4;
    *(float4*)(ps + prow)  = make_float4(s[0], s[1], s[2], s[3]);
    *(float4*)(ps2 + prow) = make_float4(s2[0], s2[1], s2[2], s2[3]);
}

__global__ __launch_bounds__(256) void k_bnfinal(const float* __restrict__ ps, const float* __restrict__ ps2,
                                                 const float* __restrict__ gamma, const float* __restrict__ beta,
                                                 float* __restrict__ scale, float* __restrict__ shift,
                                                 int P, int CH, int Nrows) {
    int t = threadIdx.x, lane = t & 63, wid = t >> 6;
    int col = blockIdx.x * 4 + wid;
    if (col >= CH) return;
    float s = 0.f, s2 = 0.f;
    for (int p = lane; p < P; p += 64) {
        s += ps[(size_t)p * CH + col];
        s2 += ps2[(size_t)p * CH + col];
    }
    #pragma unroll
    for (int m = 1; m < 64; m <<= 1) { s += __shfl_xor(s, m); s2 += __shfl_xor(s2, m); }
    if (lane == 0) {
        double mu = (double)s / Nrows;
        double var = (double)s2 / Nrows - mu * mu;
        if (var < 0) var = 0;
        float sc = gamma[col] * rsqrtf((float)var + 1e-5f);
        scale[col] = sc;
        shift[col] = beta[col] - (float)mu * sc;
    }
}

// ---------------- classifier (fused BN2+ELU on load, 64 rows/block) ----------------
__global__ __launch_bounds__(256) void k_cls(const u16* __restrict__ g2raw,
                                             const float* __restrict__ scale2, const float* __restrict__ shift2,
                                             const float* __restrict__ Wc1, const float* __restrict__ bc1,
                                             const float* __restrict__ Wc2, const float* __restrict__ bc2,
                                             float* __restrict__ out, int N) {
    __shared__ float wl[128 * 64];
    __shared__ float hs[4][128];
    int t = threadIdx.x, lane = t & 63, wid = t >> 6;
    for (int i = t; i < 128 * 64; i += 256) wl[i] = Wc1[i];
    float sc0 = scale2[2 * lane], sc1 = scale2[2 * lane + 1];
    float sh0 = shift2[2 * lane], sh1 = shift2[2 * lane + 1];
    float bb = bc1[lane];
    float c2a = Wc2[lane * 2], c2b = Wc2[lane * 2 + 1];
    float o2a = bc2[0], o2b = bc2[1];
    __syncthreads();
    int row0 = blockIdx.x * 64;
    for (int it = 0; it < 16; ++it) {
        int row = row0 + it * 4 + wid;
        if (row >= N) continue;
        const u16* hp = g2raw + (size_t)row * 128 + 2 * lane;
        float y0 = b2f(hp[0]) * sc0 + sh0; y0 = y0 > 0.f ? y0 : expm1f(y0);
        float y1 = b2f(hp[1]) * sc1 + sh1; y1 = y1 > 0.f ? y1 : expm1f(y1);
        hs[wid][2 * lane] = y0;
        hs[wid][2 * lane + 1] = y1;
        float tj = bb;
        #pragma unroll 8
        for (int c = 0; c < 128; ++c) tj += hs[wid][c] * wl[c * 64 + lane];
        tj = tj > 0.f ? tj : expm1f(tj);
        float v0 = tj * c2a, v1 = tj * c2b;
        #pragma unroll
        for (int m = 1; m < 64; m <<= 1) { v0 += __shfl_xor(v0, m); v1 += __shfl_xor(v1, m); }
        if (lane == 0) {
            out[(size_t)row * 2 + 0] = v0 + o2a;
            out[(size_t)row * 2 + 1] = v1 + o2b;
        }
    }
}

// ---------------- host launch ----------------
extern "C" void kernel_launch(void* const* d_in, const int* in_sizes, int n_in,
                              void* d_out, int out_size, void* d_ws, size_t ws_size,
                              hipStream_t stream) {
    const float* x     = (const float*)d_in[0];
    const int*   ei    = (const int*)d_in[1];
    const float* W1    = (const float*)d_in[2];
    const float* attS1 = (const float*)d_in[3];
    const float* attD1 = (const float*)d_in[4];
    const float* bn1g  = (const float*)d_in[6];
    const float* bn1b  = (const float*)d_in[7];
    const float* W2    = (const float*)d_in[8];
    const float* attS2 = (const float*)d_in[9];
    const float* attD2 = (const float*)d_in[10];
    const float* bn2g  = (const float*)d_in[12];
    const float* bn2b  = (const float*)d_in[13];
    const float* Wc1   = (const float*)d_in[14];
    const float* bc1   = (const float*)d_in[15];
    const float* Wc2   = (const float*)d_in[16];
    const float* bc2   = (const float*)d_in[17];
    float* out = (float*)d_out;

    const int DIN = 768, F1 = 1024, C2 = 128;
    int N = in_sizes[0] / DIN;                  // 20000
    int E0 = in_sizes[1] / 2;                   // 160000
    int E = E0 + N;
    const int nMB = (N + GBM - 1) / GBM;        // 157 row-blocks
    const int Mp = nMB * GBM;                   // 20096 padded rows

    char* w = (char*)d_ws;
    auto take = [&](size_t bytes) -> void* {
        void* p = (void*)w;
        w += (bytes + 255) & ~(size_t)255;
        return p;
    };
    u16* xb     = (u16*)take((size_t)Mp * DIN * 2);
    u16* bufA   = (u16*)take((size_t)N * F1 * 2);
    u16* h1b    = (u16*)take((size_t)N * F1 * 2);
    u16* w1t    = (u16*)take((size_t)F1 * DIN * 2);
    u16* w2t    = (u16*)take((size_t)C2 * F1 * 2);
    float* asrc1 = (float*)take((size_t)N * 8 * 4);
    float* adst1 = (float*)take((size_t)N * 8 * 4);
    int* deg    = (int*)take((size_t)N * 4);
    int* off    = (int*)take((size_t)(N + 1) * 4);
    int* cursor = (int*)take((size_t)N * 4);
    int* csr    = (int*)take((size_t)E * 4);
    int* flag   = (int*)take(256);
    u16* h2b    = (u16*)take((size_t)N * C2 * 2);
    float* asrc2 = (float*)take((size_t)N * 4);
    float* adst2 = (float*)take((size_t)N * 4);
    u16* g2     = (u16*)take((size_t)N * C2 * 2);
    float* scale1 = (float*)take(F1 * 4);
    float* shift1 = (float*)take(F1 * 4);
    float* scale2 = (float*)take(C2 * 4);
    float* shift2 = (float*)take(C2 * 4);
    float* psA   = (float*)take((size_t)1024 * 1024 * 4);
    float* psB   = (float*)take((size_t)1024 * 1024 * 4);
    float* part  = (float*)h1b;  // split-K partials alias h1b (dead after k_agg1)

    size_t n4 = (size_t)N * DIN / 4;
    int nAtt = (N + 1) / 2;

    // 1. pre: cast + deg-zero + detect + weight transposes
    k_pre<<<2048 + 896, 256, 0, stream>>>(x, xb, W1, w1t, W2, w2t, ei, flag, deg, n4, E0, N);

    // 2. layer 1 GEMM, then fused att-dots + degree histogram
    k_gemm<<<nMB * (F1 / GBN), 256, 0, stream>>>(xb, w1t, h1b, N, F1, DIN, F1 / GBN);
    k_attdeg<<<nAtt + 512, 256, 0, stream>>>(h1b, attS1, attD1, asrc1, adst1, ei, flag, deg, N, E0, E, nAtt);

    // 3. CSR scan + scatter
    k_scan<<<1, 1024, 0, stream>>>(deg, off, cursor, N);
    k_scatter<<<512, 256, 0, stream>>>(ei, flag, cursor, csr, E0, E);

    // 4. layer 1: fused softmax+gather -> BN stats
    k_agg1<<<N, 256, 0, stream>>>(off, csr, asrc1, adst1, h1b, bufA, N);
    {
        int nchunk = 256, rpc = (N + nchunk - 1) / nchunk;
        k_bnpart<1024><<<nchunk, 256, 0, stream>>>(bufA, psA, psB, N, rpc);
        k_bnfinal<<<F1 / 4, 256, 0, stream>>>(psA, psB, bn1g, bn1b, scale1, shift1, nchunk, F1, N);
    }

    // 5. layer 2 GEMM (split-K, BN1+ELU fused) + reduce + att dots
    k_gemm2<<<dim3(nMB, SPLITK), 256, 0, stream>>>(bufA, w2t, part, N, F1, scale1, shift1);
    k_red2<<<(N + 3) / 4, 256, 0, stream>>>(part, attS2, attD2, h2b, asrc2, adst2, N);

    // 6. layer 2: fused softmax+gather -> BN stats
    k_agg2<<<N, 128, 0, stream>>>(off, csr, asrc2, adst2, h2b, g2, N);
    {
        int nchunk = 128, rpc = (N + nchunk - 1) / nchunk;
        k_bnpart<128><<<nchunk, 256, 0, stream>>>(g2, psA, psB, N, rpc);
        k_bnfinal<<<C2 / 4, 256, 0, stream>>>(psA, psB, bn2g, bn2b, scale2, shift2, nchunk * 8, C2, N);
    }

    // 7. classifier head (fused BN2+ELU)
    k_cls<<<(N + 63) / 64, 256, 0, stream>>>(g2, scale2, shift2, Wc1, bc1, Wc2, bc2, out, N);
}